// Round 5
// baseline (511.729 us; speedup 1.0000x reference)
//
#include <hip/hip_runtime.h>
#include <hip/hip_bf16.h>

typedef __bf16 bf16;
typedef __attribute__((ext_vector_type(8))) __bf16 bf16x8;
typedef __attribute__((ext_vector_type(4))) float f32x4;

#define IN_F 4096
#define UNITS 4096
#define BATCH 8192
#define NNZ_CNT 1677721
#define KPC 409                 // NNZ // UNITS (exact, by construction)
#define BASE_CNT (KPC * UNITS)  // entries [0,BASE_CNT) have col = i/KPC
#define NT 64                   // K-tiles of 64
#define NITER 32                // 2 K-tiles per iteration

// async global->LDS, 16B per lane (lands at firstlane_addr + lane*16)
#define GLOAD_LDS16(g, l)                                              \
  __builtin_amdgcn_global_load_lds(                                    \
      (const __attribute__((address_space(1))) void*)(g),              \
      (__attribute__((address_space(3))) void*)(l), 16, 0, 0)

// raw barrier: no vmcnt(0) drain (counted vmcnt keeps loads in flight)
#define S_BARRIER() asm volatile("s_barrier" ::: "memory")
#define VMCNT4() asm volatile("s_waitcnt vmcnt(4)" ::: "memory")
#define LGKM8() asm volatile("s_waitcnt lgkmcnt(8)" ::: "memory")
#define LGKM0() asm volatile("s_waitcnt lgkmcnt(0)" ::: "memory")
#define SCHED0() __builtin_amdgcn_sched_barrier(0)
#define PRIO1() __builtin_amdgcn_s_setprio(1)
#define PRIO0() __builtin_amdgcn_s_setprio(0)

// inline-asm ds_read_b128: invisible to the compiler's LDS alias analysis, so
// no conservative vmcnt waits get attached; we own all waits explicitly.
#define DSR(dst, ad, off) \
  asm volatile("ds_read_b128 %0, %1 offset:" off : "=v"(dst) : "v"(ad))

// ---------------------------------------------------------------------------
// Build W^T column-strips in LDS: block c zeroes W^T row c, scatters its KPC
// base entries (col = i/KPC by construction), streams out coalesced.
// ---------------------------------------------------------------------------
__global__ __launch_bounds__(256) void col_build_kernel(
    const float* __restrict__ vals, const int* __restrict__ rows,
    bf16* __restrict__ Wt) {
  __shared__ bf16 w[IN_F];  // 8 KB
  const int c = blockIdx.x;
  const int t = threadIdx.x;
  const bf16x8 z = {};
#pragma unroll
  for (int i = 0; i < 2; ++i) ((bf16x8*)w)[t + i * 256] = z;
  __syncthreads();
#pragma unroll
  for (int j = t; j < KPC; j += 256) {
    const int idx = c * KPC + j;
    w[rows[idx]] = (bf16)vals[idx];
  }
  __syncthreads();
  bf16x8* dst = (bf16x8*)(Wt + (size_t)c * IN_F);
#pragma unroll
  for (int i = 0; i < 2; ++i) dst[t + i * 256] = ((bf16x8*)w)[t + i * 256];
}

// the NNZ % UNITS = 2457 "remain" entries (random cols) — after col_build
__global__ __launch_bounds__(256) void extras_kernel(
    const float* __restrict__ vals, const int* __restrict__ rows,
    const int* __restrict__ cols, bf16* __restrict__ Wt) {
  int i = BASE_CNT + blockIdx.x * 256 + threadIdx.x;
  if (i < NNZ_CNT) Wt[(size_t)cols[i] * IN_F + rows[i]] = (bf16)vals[i];
}

// x fp32 -> bf16, 8 elems/thread
__global__ __launch_bounds__(256) void cvt_x_kernel(const float* __restrict__ x,
                                                    bf16* __restrict__ xb) {
  size_t i = ((size_t)blockIdx.x * 256 + threadIdx.x) * 8;
  float4 v0 = *(const float4*)(x + i);
  float4 v1 = *(const float4*)(x + i + 4);
  bf16x8 o;
  o[0] = (bf16)v0.x; o[1] = (bf16)v0.y; o[2] = (bf16)v0.z; o[3] = (bf16)v0.w;
  o[4] = (bf16)v1.x; o[5] = (bf16)v1.y; o[6] = (bf16)v1.z; o[7] = (bf16)v1.w;
  *(bf16x8*)(xb + i) = o;
}

// stage one 16KB half-tile: 512 threads x 2 x 16B. LDS dest linear (slot =
// tid, tid+512); global source pre-permuted to frag-linear order (rule #21).
__device__ __forceinline__ void stage2(const bf16* s0, bf16* l, int tid) {
  GLOAD_LDS16(s0, l + tid * 8);
  GLOAD_LDS16(s0 + 128 * (long)IN_F, l + 4096 + tid * 8);
}

// one C-quadrant (MH,NH) x K=64: 16 x mfma_f32_16x16x32_bf16
// (8 independent acc chains of depth 2 — keeps the matrix pipe fed)
template <int MH, int NH>
__device__ __forceinline__ void mfma_quad(const bf16x8 (&a)[8],
                                          const bf16x8 (&b)[2][4],
                                          f32x4 (&acc)[8][4]) {
#pragma unroll
  for (int im = 0; im < 4; ++im)
#pragma unroll
    for (int in = 0; in < 2; ++in)
#pragma unroll
      for (int ks = 0; ks < 2; ++ks)
        acc[MH * 4 + im][NH * 2 + in] =
            __builtin_amdgcn_mfma_f32_16x16x32_bf16(
                a[im * 2 + ks], b[NH][in * 2 + ks],
                acc[MH * 4 + im][NH * 2 + in], 0, 0, 0);
}

// ---------------------------------------------------------------------------
// 256x256 8-phase bf16 GEMM, 16x16x32 MFMA, frag-linear LDS, asm ds_read.
// 8 waves (2M x 4N), per-wave 128x64 out = 4x2 quadrant layout (16 MFMA/phase).
// LDS 128KB: 8 halves x 16KB; each half = 16 frag-slots of 1024B; slot holds
// exactly one wave-fragment (lane l -> l*16B) -> contiguous 1KB ds_read_b128,
// zero bank conflicts by construction.
// A-half h slot f: wm=f>>3, im=(f>>1)&3, ks=f&1;
//   row = wm*128 + h*64 + im*16 + (l&15); k = ks*32 + (l>>4)*8.
// B-half h slot f: wn=f>>2, in=(f>>1)&1, ks=f&1;
//   n = wn*64 + h*32 + in*16 + (l&15); same k.  (load2 = +128 rows for both)
// ---------------------------------------------------------------------------
__global__ __launch_bounds__(512, 2) void gemm8_kernel(
    const bf16* __restrict__ A, const bf16* __restrict__ Bt,
    const float* __restrict__ bias, float* __restrict__ C) {
  __shared__ bf16 lds[65536];  // 128 KB

  const int tid = threadIdx.x;
  const int lane = tid & 63;
  const int wave = tid >> 6;
  const int wm = wave >> 2;  // 0..1
  const int wn = wave & 3;   // 0..3

  // XCD-aware swizzle (512 blocks, %8==0 -> bijective); each XCD owns 2 full
  // N-columns (B panel fits its 4MB L2).
  const int sb = (blockIdx.x & 7) * 64 + (blockIdx.x >> 3);
  const long m0 = (long)(sb & 31) * 256;
  const long n0 = (long)(sb >> 5) * 256;

  // ---- staging source (frag-linear permutation), per-thread constant ----
  const int f = tid >> 6;  // slot 0..7 (load1); load2 hits slots 8..15
  const int l = tid & 63;
  const int kL = (f & 1) * 32 + ((l >> 4) & 3) * 8;
  const int rA = ((f >> 1) & 3) * 16 + (l & 15);
  const int rB = ((f >> 2) & 1) * 64 + ((f >> 1) & 1) * 16 + (l & 15);
  const bf16* gA = A + (m0 + rA) * (long)IN_F + kL;
  const bf16* gB = Bt + (n0 + rB) * (long)IN_F + kL;

  // ---- asm ds_read base addresses (32-bit LDS byte offsets) ----
  const unsigned ldsb =
      (unsigned)(uintptr_t)(__attribute__((address_space(3))) bf16*)lds;
  const unsigned aBase = ldsb + wm * 8192 + lane * 16;
  const unsigned bBase = ldsb + wn * 4096 + lane * 16;

  bf16x8 a[8];     // current A m-half: [im*2+ks]
  bf16x8 b[2][4];  // both B n-halves:  [nh][in*2+ks]
  f32x4 acc[8][4] = {};

#define LDSA(buf, h) (lds + ((buf) * 4 + (h)) * 8192)
#define LDSB(buf, h) (lds + ((buf) * 4 + 2 + (h)) * 8192)
#define STAGE_A(buf, h, kt) \
  stage2(gA + (h) * 64 * (long)IN_F + (kt) * 64, LDSA(buf, h), tid)
#define STAGE_B(buf, h, kt) \
  stage2(gB + (h) * 32 * (long)IN_F + (kt) * 64, LDSB(buf, h), tid)
#define LOAD_A(buf, mh)                                              \
  {                                                                  \
    unsigned _ad = aBase + (unsigned)(((buf) * 4 + (mh)) * 16384);   \
    DSR(a[0], _ad, "0");    DSR(a[1], _ad, "1024");                  \
    DSR(a[2], _ad, "2048"); DSR(a[3], _ad, "3072");                  \
    DSR(a[4], _ad, "4096"); DSR(a[5], _ad, "5120");                  \
    DSR(a[6], _ad, "6144"); DSR(a[7], _ad, "7168");                  \
  }
#define LOAD_BH(buf, nh)                                                 \
  {                                                                      \
    unsigned _bd = bBase + (unsigned)(((buf) * 4 + 2 + (nh)) * 16384);   \
    DSR(b[nh][0], _bd, "0");    DSR(b[nh][1], _bd, "1024");              \
    DSR(b[nh][2], _bd, "2048"); DSR(b[nh][3], _bd, "3072");              \
  }

  // ---- prologue: K-tile 0 fully into buf0; A0,B0 of K-tile 1 into buf1 ----
  STAGE_A(0, 0, 0);
  STAGE_A(0, 1, 0);
  STAGE_B(0, 0, 0);
  STAGE_B(0, 1, 0);
  STAGE_A(1, 0, 1);
  STAGE_B(1, 0, 1);
  VMCNT4();  // 12 issued, oldest 8 (= all of K-tile 0) landed
  S_BARRIER();

  for (int i = 0; i < NITER; ++i) {
    const int t1 = 2 * i + 1;
    const int t2 = (2 * i + 2) & (NT - 1);  // wraps harmlessly on last iter
    const int t3 = (2 * i + 3) & (NT - 1);

    // ======== phases 0-3: compute buf0 (K-tile 2i) ========
    LOAD_A(0, 0); LOAD_BH(0, 0);  // 12 ds_reads
    STAGE_A(1, 1, t1);
    LGKM8();
    S_BARRIER(); LGKM0(); SCHED0();
    PRIO1(); mfma_quad<0, 0>(a, b, acc); PRIO0(); SCHED0(); S_BARRIER();

    LOAD_BH(0, 1);                 // 4 ds_reads
    STAGE_B(1, 1, t1);
    S_BARRIER(); LGKM0(); SCHED0();
    PRIO1(); mfma_quad<0, 1>(a, b, acc); PRIO0(); SCHED0(); S_BARRIER();

    LOAD_A(0, 1);                  // 8 ds_reads
    STAGE_A(0, 0, t2);
    S_BARRIER(); LGKM0(); SCHED0();
    PRIO1(); mfma_quad<1, 0>(a, b, acc); PRIO0(); SCHED0(); S_BARRIER();

    STAGE_B(0, 0, t2);             // 0 ds_reads
    S_BARRIER(); SCHED0();
    PRIO1(); mfma_quad<1, 1>(a, b, acc); PRIO0(); SCHED0();
    VMCNT4();  // outstanding p2,p3 stages -> everything through p1 landed
    S_BARRIER();

    // ======== phases 4-7: compute buf1 (K-tile 2i+1) ========
    LOAD_A(1, 0); LOAD_BH(1, 0);
    STAGE_A(0, 1, t2);
    LGKM8();
    S_BARRIER(); LGKM0(); SCHED0();
    PRIO1(); mfma_quad<0, 0>(a, b, acc); PRIO0(); SCHED0(); S_BARRIER();

    LOAD_BH(1, 1);
    STAGE_B(0, 1, t2);
    S_BARRIER(); LGKM0(); SCHED0();
    PRIO1(); mfma_quad<0, 1>(a, b, acc); PRIO0(); SCHED0(); S_BARRIER();

    LOAD_A(1, 1);
    STAGE_A(1, 0, t3);
    S_BARRIER(); LGKM0(); SCHED0();
    PRIO1(); mfma_quad<1, 0>(a, b, acc); PRIO0(); SCHED0(); S_BARRIER();

    STAGE_B(1, 0, t3);
    S_BARRIER(); SCHED0();
    PRIO1(); mfma_quad<1, 1>(a, b, acc); PRIO0(); SCHED0();
    VMCNT4();  // outstanding p6,p7 stages -> everything through p5 landed
    S_BARRIER();
  }

  // ---- epilogue: bias + relu, fp32 C ----
  // C/D layout (m89): col = lane&15, row = (lane>>4)*4 + ii
#pragma unroll
  for (int ni = 0; ni < 4; ++ni) {
    const long n = n0 + wn * 64 + (ni >> 1) * 32 + (ni & 1) * 16 + (lane & 15);
    const float bv = bias[n];
#pragma unroll
    for (int mi = 0; mi < 8; ++mi) {
      const long mrow =
          m0 + wm * 128 + (mi >> 2) * 64 + (mi & 3) * 16 + ((lane >> 4) << 2);
      float* cp = C + mrow * UNITS + n;
#pragma unroll
      for (int ii = 0; ii < 4; ++ii) {
        float v = acc[mi][ni][ii] + bv;
        cp[(long)ii * UNITS] = v > 0.f ? v : 0.f;
      }
    }
  }
#undef LDSA
#undef LDSB
#undef STAGE_A
#undef STAGE_B
#undef LOAD_A
#undef LOAD_BH
}

extern "C" void kernel_launch(void* const* d_in, const int* in_sizes, int n_in,
                              void* d_out, int out_size, void* d_ws,
                              size_t ws_size, hipStream_t stream) {
  const float* x = (const float*)d_in[0];     // [8192][4096] fp32
  const float* kern = (const float*)d_in[1];  // [NNZ] fp32
  const float* bias = (const float*)d_in[2];  // [4096] fp32
  const int* rows = (const int*)d_in[3];      // [NNZ] int32
  const int* cols = (const int*)d_in[4];      // [NNZ] int32
  float* out = (float*)d_out;                 // [8192][4096] fp32

  bf16* Wt = (bf16*)d_ws;
  bf16* xb = (bf16*)((char*)d_ws + (size_t)UNITS * IN_F * sizeof(bf16));

  col_build_kernel<<<UNITS, 256, 0, stream>>>(kern, rows, Wt);
  extras_kernel<<<(NNZ_CNT - BASE_CNT + 255) / 256, 256, 0, stream>>>(
      kern, rows, cols, Wt);
  cvt_x_kernel<<<(size_t)BATCH * IN_F / 8 / 256, 256, 0, stream>>>(x, xb);

  gemm8_kernel<<<512, 512, 0, stream>>>(xb, Wt, bias, out);
}